// Round 4
// baseline (261.164 us; speedup 1.0000x reference)
//
#include <hip/hip_runtime.h>
#include <hip/hip_bf16.h>
#include <math.h>

#define N_TOK 16384
#define DIM   2048
#define NE    64
#define TOPK  9

#define ROWS     16            // rows per block
#define DC       64            // k-elements per chunk
#define NCHUNK   (DIM / DC)    // 32
#define NTHREADS 256           // 4 waves; wave w owns col-tiles {2w, 2w+1}
#define NBUF     4             // x-stage ring depth (prefetch depth 3)

typedef short  short8  __attribute__((ext_vector_type(8)));
typedef float  float4_ __attribute__((ext_vector_type(4)));
typedef unsigned short ushort_t;

__device__ __forceinline__ void async16(const void* g, void* l) {
    __builtin_amdgcn_global_load_lds(
        (const __attribute__((address_space(1))) void*)g,
        (__attribute__((address_space(3))) void*)l, 16, 0, 0);
}

__device__ __forceinline__ unsigned pk2(float a, float b) {
    float2 f; f.x = a; f.y = b;
    __hip_bfloat162 h = __float22bfloat162_rn(f);   // low16 = bf16(a)
    unsigned u;
    __builtin_memcpy(&u, &h, 4);
    return u;
}

// 8 fp32 -> bf16 hi frag + bf16 lo frag (2-term split)
__device__ __forceinline__ void cvt8(const float4_ va, const float4_ vb,
                                     short8* h, short8* l) {
    union { short8 s; unsigned u[4]; } H, L;
    const float f[8] = {va[0], va[1], va[2], va[3], vb[0], vb[1], vb[2], vb[3]};
#pragma unroll
    for (int i = 0; i < 4; ++i) {
        const float a = f[2 * i], b = f[2 * i + 1];
        const unsigned p = pk2(a, b);
        H.u[i] = p;
        const float ha = __uint_as_float(p << 16);
        const float hb = __uint_as_float(p & 0xffff0000u);
        L.u[i] = pk2(a - ha, b - hb);
    }
    *h = H.s; *l = L.s;
}

__device__ __forceinline__ void wave_max64_2(float& a, float& b) {
#pragma unroll
    for (int off = 32; off > 0; off >>= 1) {
        const float ax = __shfl_xor(a, off, 64);
        const float bx = __shfl_xor(b, off, 64);
        a = fmaxf(a, ax);
        b = fmaxf(b, bx);
    }
}

__device__ __forceinline__ void wave_sum64_3(float& a, float& b, float& c) {
#pragma unroll
    for (int off = 32; off > 0; off >>= 1) {
        const float ax = __shfl_xor(a, off, 64);
        const float bx = __shfl_xor(b, off, 64);
        const float cx = __shfl_xor(c, off, 64);
        a += ax;
        b += bx;
        c += cx;
    }
}

// ---- prep: Wr|Wn (fp32, D x 64 each) -> B-fragment-ordered bf16 hi/lo ----
// slot s=(kcg*8+ct)*2+t holds 512 bf16: elem l*8+j = B[k=kcg*32+(l>>4)*8+j][n=ct*16+(l&15)]
__global__ __launch_bounds__(256)
void prep_w(const float* __restrict__ Wr, const float* __restrict__ Wn,
            ushort_t* __restrict__ wsW)
{
    const int gid = blockIdx.x * 256 + threadIdx.x;   // [0, 64*8*64)
    const int l   = gid & 63;
    const int ct  = (gid >> 6) & 7;
    const int kcg = gid >> 9;                         // 0..63
    const int n   = ct * 16 + (l & 15);
    const int k0  = kcg * 32 + (l >> 4) * 8;
    const float* src = (n < NE) ? (Wr + n) : (Wn + (n - NE));
    union { short8 s; ushort_t us[8]; } H, L;
#pragma unroll
    for (int j = 0; j < 8; ++j) {
        const float v = src[(size_t)(k0 + j) * NE];
        const unsigned uv = __float_as_uint(v);
        const unsigned hb = (uv + 0x7fffu + ((uv >> 16) & 1u)) & 0xffff0000u;
        const float lo = v - __uint_as_float(hb);
        const unsigned ul = __float_as_uint(lo);
        H.us[j] = (ushort_t)(hb >> 16);
        L.us[j] = (ushort_t)((ul + 0x7fffu + ((ul >> 16) & 1u)) >> 16);
    }
    const size_t s0 = (size_t)(kcg * 8 + ct) * 2;     // slot pair index
    *(short8*)(wsW + s0 * 512 + l * 8)         = H.s;
    *(short8*)(wsW + (s0 + 1) * 512 + l * 8)   = L.s;
}

// B fragments for one chunk, double-buffered in registers across chunks.
struct BFrag { short8 h[2][2]; short8 l[2][2]; };

__device__ __forceinline__ void load_b(const char* __restrict__ wsB,
                                       int ch, int w, int lane, BFrag& b) {
#pragma unroll
    for (int kc = 0; kc < 2; ++kc)
#pragma unroll
        for (int cc = 0; cc < 2; ++cc) {
            const size_t off = (size_t)(((ch * 2 + kc) * 8) + 2 * w + cc) * 2048
                             + (size_t)lane * 16;
            b.h[kc][cc] = *(const short8*)(wsB + off);
            b.l[kc][cc] = *(const short8*)(wsB + off + 1024);
        }
}

// one row-tile (16 rows) x 2 col-tiles x 64 k
__device__ __forceinline__ void mfma_chunk(const float* __restrict__ xb,
                                           const int (&aoff)[2][2],
                                           const BFrag& b,
                                           float4_ (&acc)[2]) {
#pragma unroll
    for (int kc = 0; kc < 2; ++kc) {
        const float4_ va = *(const float4_*)(xb + aoff[kc][0]);
        const float4_ vb = *(const float4_*)(xb + aoff[kc][1]);
        short8 ah, al;
        cvt8(va, vb, &ah, &al);
#pragma unroll
        for (int cc = 0; cc < 2; ++cc) {
            acc[cc] = __builtin_amdgcn_mfma_f32_16x16x32_bf16(ah, b.h[kc][cc], acc[cc], 0, 0, 0);
            acc[cc] = __builtin_amdgcn_mfma_f32_16x16x32_bf16(al, b.h[kc][cc], acc[cc], 0, 0, 0);
            acc[cc] = __builtin_amdgcn_mfma_f32_16x16x32_bf16(ah, b.l[kc][cc], acc[cc], 0, 0, 0);
        }
    }
}

__global__ __launch_bounds__(NTHREADS, 4)
void moe_main(const float* __restrict__ x,
              const float* __restrict__ br,
              const float* __restrict__ bn,
              const float* __restrict__ noise_eps,
              const float* __restrict__ gumbel,
              const ushort_t* __restrict__ wsW,
              float* __restrict__ out)
{
    // x stage ring: 4 x 1024 floats (16 KB); epilogue: 2 x 16 x 65 = 2080x2
    __shared__ __align__(16) float smem[4352];

    const int t    = threadIdx.x;
    const int lane = t & 63;
    const int w    = t >> 6;          // wave 0..3, owns col-tiles {2w, 2w+1}
    const int c4   = lane & 15;
    const int q    = lane >> 4;
    const int row0 = blockIdx.x * ROWS;

    // x staging: 4 issues/chunk, wave w does issue i=w covering rows 4w..4w+3
    // lane l -> row 4w+(l>>4); LDS granule pos p=l&15 holds gk = p^(row&15)
    const int  srow = 4 * w + q;
    const int  sgk  = c4 ^ (srow & 15);
    const float* gxb = x + (size_t)(row0 + srow) * DIM + sgk * 4;
    const int  lxo  = w * 256;        // float offset within a stage buffer

    // A-read offsets (chunk-invariant): row m=c4, granules (kc*8+q*2)^c4, +1^c4
    int aoff[2][2];
#pragma unroll
    for (int kc = 0; kc < 2; ++kc) {
        const int g0 = kc * 8 + q * 2;
        aoff[kc][0] = c4 * 64 + ((g0 ^ c4) * 4);
        aoff[kc][1] = c4 * 64 + (((g0 + 1) ^ c4) * 4);
    }

    float4_ acc[2];
    acc[0] = (float4_)(0.f);
    acc[1] = (float4_)(0.f);

    const char* wsB = (const char*)wsW;

    // ---- prologue: stage chunks 0..2 (depth 3), B(0) into regs ----
#pragma unroll
    for (int p = 0; p < NBUF - 1; ++p)
        async16(gxb + p * DC, &smem[p * 1024 + lxo]);

    BFrag bA, bB;
    load_b(wsB, 0, w, lane, bA);

    // Steady step i: outstanding at top = S(i) + S(i+1) + S(i+2) + B(i):8 = 11
    // -> vmcnt(10) retires exactly S(i). Tail steps use exact counts.
#pragma unroll 1
    for (int i = 0; i < NCHUNK - 4; i += 2) {
        // ---- even step: use bA, prefetch bB ----
        asm volatile("s_waitcnt vmcnt(10)" ::: "memory");
        __builtin_amdgcn_s_barrier();
        asm volatile("" ::: "memory");
        load_b(wsB, i + 1, w, lane, bB);
        async16(gxb + (i + 3) * DC, &smem[((i + 3) & 3) * 1024 + lxo]);
        __builtin_amdgcn_sched_barrier(0);   // pin load-issues above compute
        mfma_chunk(&smem[(i & 3) * 1024], aoff, bA, acc);

        // ---- odd step: use bB, prefetch bA ----
        asm volatile("s_waitcnt vmcnt(10)" ::: "memory");
        __builtin_amdgcn_s_barrier();
        asm volatile("" ::: "memory");
        load_b(wsB, i + 2, w, lane, bA);
        async16(gxb + (i + 4) * DC, &smem[((i + 4) & 3) * 1024 + lxo]);
        __builtin_amdgcn_sched_barrier(0);
        mfma_chunk(&smem[((i + 1) & 3) * 1024], aoff, bB, acc);
    }

    // ---- tail: steps 28..31 ----
    // step 28: outstanding S28 S29 S30 B28 = 11 -> vmcnt(10)
    asm volatile("s_waitcnt vmcnt(10)" ::: "memory");
    __builtin_amdgcn_s_barrier();
    asm volatile("" ::: "memory");
    load_b(wsB, 29, w, lane, bB);
    async16(gxb + 31 * DC, &smem[3 * 1024 + lxo]);
    __builtin_amdgcn_sched_barrier(0);
    mfma_chunk(&smem[0 * 1024], aoff, bA, acc);

    // step 29: outstanding S29 S30 S31 B29 = 11 -> vmcnt(10)
    asm volatile("s_waitcnt vmcnt(10)" ::: "memory");
    __builtin_amdgcn_s_barrier();
    asm volatile("" ::: "memory");
    load_b(wsB, 30, w, lane, bA);
    __builtin_amdgcn_sched_barrier(0);
    mfma_chunk(&smem[1 * 1024], aoff, bB, acc);

    // step 30: outstanding S30 S31 B30 = 10 -> vmcnt(9)
    asm volatile("s_waitcnt vmcnt(9)" ::: "memory");
    __builtin_amdgcn_s_barrier();
    asm volatile("" ::: "memory");
    load_b(wsB, 31, w, lane, bB);
    __builtin_amdgcn_sched_barrier(0);
    mfma_chunk(&smem[2 * 1024], aoff, bA, acc);

    // step 31: outstanding S31 B31 = 9 -> vmcnt(8)
    asm volatile("s_waitcnt vmcnt(8)" ::: "memory");
    __builtin_amdgcn_s_barrier();
    asm volatile("" ::: "memory");
    __builtin_amdgcn_sched_barrier(0);
    mfma_chunk(&smem[3 * 1024], aoff, bB, acc);

    // prefetch per-row randomness early (overlaps epilogue barrier+transpose)
    float epsv[4], gumv[4];
#pragma unroll
    for (int r = 0; r < 4; ++r) {
        const int row = row0 + w * 4 + r;
        epsv[r] = noise_eps[(size_t)row * NE + lane];
        gumv[r] = gumbel  [(size_t)row * NE + lane];
    }

    // ---- epilogue: transpose C tiles through LDS, then per-row wave ops ----
    __syncthreads();                   // all ring reads done; reuse LDS
    float* rawS = &smem[0];            // 16 x 65 (padded)
    float* noiS = &smem[2080];         // 16 x 65
#pragma unroll
    for (int cc = 0; cc < 2; ++cc) {
        const int colg = (2 * w + cc) * 16 + c4;   // 0..127; <64 raw else noise
        float* basep = (colg < NE) ? rawS : noiS;
        const int col = colg & 63;
#pragma unroll
        for (int v = 0; v < 4; ++v) {
            const int row = q * 4 + v;             // C/D: col=lane&15, row=quad*4+reg
            basep[row * 65 + col] = acc[cc][v];
        }
    }
    __syncthreads();

    const float br_l = br[lane];
    const float bn_l = bn[lane];

    float imp_acc = 0.f, load_acc = 0.f;
    float* out_em   = out;
    float* out_rp   = out + (size_t)N_TOK * NE;
    float* out_imp  = out + (size_t)2 * N_TOK * NE;
    float* out_load = out_imp + NE;

#pragma unroll 1
    for (int r = 0; r < 4; ++r) {
        const int lrow = w * 4 + r;
        const int row  = row0 + lrow;
        const float raw = rawS[lrow * 65 + lane] + br_l;
        const float nl  = noiS[lrow * 65 + lane] + bn_l;
        const float sd = fmaxf(nl, 0.f) + log1pf(expf(-fabsf(nl))) + 0.01f;
        const float noisy = fmaf(epsv[r], sd, raw);

        // ---- threshold = 9th largest via ballot binary search (bit-exact) ----
        const unsigned uk  = __float_as_uint(noisy);
        const unsigned key = uk ^ ((uk & 0x80000000u) ? 0xFFFFFFFFu : 0x80000000u);
        unsigned res = 0;
#pragma unroll
        for (int bit = 31; bit >= 0; --bit) {
            const unsigned cand = res | (1u << bit);
            const int cnt = __popcll(__ballot(key >= cand));
            if (cnt >= TOPK) res = cand;
        }
        const float thr  = __uint_as_float(res ^ ((res & 0x80000000u) ? 0x80000000u : 0xFFFFFFFFu));
        const float hard = (key >= res) ? 1.f : 0.f;

        // fused reductions: one dual-max chain, one triple-sum chain
        const float g = noisy + gumv[r];
        float mg = g, mr = raw;
        wave_max64_2(mg, mr);

        const float eg = expf(g - mg);
        const float en = expf(noisy - thr);   // softmax shift-invariant
        const float er = expf(raw - mr);
        float sg = eg, sn = en, sr = er;
        wave_sum64_3(sg, sn, sr);

        const float ms = eg / sg;
        const float em = (hard - ms) + ms;
        const float rp = en / sn;
        imp_acc += er / sr;

        const float z = (thr - raw) / sd;
        load_acc += 0.5f * erfcf(z * 45.254833995939045f);

        out_em[(size_t)row * NE + lane] = em;
        out_rp[(size_t)row * NE + lane] = rp;
    }

    __syncthreads();                   // rawS/noiS reads done; reuse for reduction
    smem[w * 64 + lane]       = imp_acc;
    smem[256 + w * 64 + lane] = load_acc;
    __syncthreads();
    if (w == 0) {
        const float s1 = smem[lane] + smem[64 + lane] + smem[128 + lane] + smem[192 + lane];
        const float s2 = smem[256 + lane] + smem[320 + lane] + smem[384 + lane] + smem[448 + lane];
        atomicAdd(&out_imp[lane], s1);
        atomicAdd(&out_load[lane], s2);
    }
}

extern "C" void kernel_launch(void* const* d_in, const int* in_sizes, int n_in,
                              void* d_out, int out_size, void* d_ws, size_t ws_size,
                              hipStream_t stream)
{
    const float* x         = (const float*)d_in[0];
    const float* Wr        = (const float*)d_in[1];
    const float* br        = (const float*)d_in[2];
    const float* Wn        = (const float*)d_in[3];
    const float* bn        = (const float*)d_in[4];
    const float* noise_eps = (const float*)d_in[5];
    const float* gumbel    = (const float*)d_in[6];
    float* out = (float*)d_out;
    ushort_t* wsW = (ushort_t*)d_ws;   // 1 MB (64*8*2 slots x 1 KB)

    (void)hipMemsetAsync((char*)d_out + (size_t)2 * N_TOK * NE * sizeof(float), 0,
                         2 * NE * sizeof(float), stream);
    prep_w<<<128, 256, 0, stream>>>(Wr, Wn, wsW);
    moe_main<<<N_TOK / ROWS, NTHREADS, 0, stream>>>(
        x, br, bn, noise_eps, gumbel, wsW, out);
}

// Round 5
// 260.785 us; speedup vs baseline: 1.0015x; 1.0015x over previous
//
#include <hip/hip_runtime.h>
#include <hip/hip_bf16.h>
#include <math.h>

#define N_TOK 16384
#define DIM   2048
#define NE    64
#define TOPK  9

#define ROWS     16            // rows per block
#define DC       64            // k-elements per chunk
#define NCHUNK   (DIM / DC)    // 32
#define NTHREADS 256           // 4 waves; wave w owns col-tiles {2w, 2w+1}
#define NBUF     8             // x-stage ring slots (4KB each); prefetch depth 3

typedef short  short8  __attribute__((ext_vector_type(8)));
typedef float  float4_ __attribute__((ext_vector_type(4)));
typedef unsigned short ushort_t;

__device__ __forceinline__ void async16(const void* g, void* l) {
    __builtin_amdgcn_global_load_lds(
        (const __attribute__((address_space(1))) void*)g,
        (__attribute__((address_space(3))) void*)l, 16, 0, 0);
}

// LDS read the compiler cannot see as depending on global_load_lds:
// no auto vmcnt(0) drain gets inserted. Pair with explicit lgkmcnt(0)+SB.
__device__ __forceinline__ float4_ ds_read128(unsigned addr) {
    float4_ d;
    asm volatile("ds_read_b128 %0, %1" : "=v"(d) : "v"(addr));
    return d;
}

__device__ __forceinline__ unsigned pk2(float a, float b) {
    float2 f; f.x = a; f.y = b;
    __hip_bfloat162 h = __float22bfloat162_rn(f);   // low16 = bf16(a)
    unsigned u;
    __builtin_memcpy(&u, &h, 4);
    return u;
}

// 8 fp32 -> bf16 hi frag + bf16 lo frag (2-term split)
__device__ __forceinline__ void cvt8(const float4_ va, const float4_ vb,
                                     short8* h, short8* l) {
    union { short8 s; unsigned u[4]; } H, L;
    const float f[8] = {va[0], va[1], va[2], va[3], vb[0], vb[1], vb[2], vb[3]};
#pragma unroll
    for (int i = 0; i < 4; ++i) {
        const float a = f[2 * i], b = f[2 * i + 1];
        const unsigned p = pk2(a, b);
        H.u[i] = p;
        const float ha = __uint_as_float(p << 16);
        const float hb = __uint_as_float(p & 0xffff0000u);
        L.u[i] = pk2(a - ha, b - hb);
    }
    *h = H.s; *l = L.s;
}

__device__ __forceinline__ void wave_max64_2(float& a, float& b) {
#pragma unroll
    for (int off = 32; off > 0; off >>= 1) {
        const float ax = __shfl_xor(a, off, 64);
        const float bx = __shfl_xor(b, off, 64);
        a = fmaxf(a, ax);
        b = fmaxf(b, bx);
    }
}

__device__ __forceinline__ void wave_sum64_3(float& a, float& b, float& c) {
#pragma unroll
    for (int off = 32; off > 0; off >>= 1) {
        const float ax = __shfl_xor(a, off, 64);
        const float bx = __shfl_xor(b, off, 64);
        const float cx = __shfl_xor(c, off, 64);
        a += ax;
        b += bx;
        c += cx;
    }
}

// ---- prep: Wr|Wn (fp32, D x 64 each) -> B-fragment-ordered bf16 hi/lo ----
// slot s=(kcg*8+ct)*2+t holds 512 bf16: elem l*8+j = B[k=kcg*32+(l>>4)*8+j][n=ct*16+(l&15)]
__global__ __launch_bounds__(256)
void prep_w(const float* __restrict__ Wr, const float* __restrict__ Wn,
            ushort_t* __restrict__ wsW)
{
    const int gid = blockIdx.x * 256 + threadIdx.x;   // [0, 64*8*64)
    const int l   = gid & 63;
    const int ct  = (gid >> 6) & 7;
    const int kcg = gid >> 9;                         // 0..63
    const int n   = ct * 16 + (l & 15);
    const int k0  = kcg * 32 + (l >> 4) * 8;
    const float* src = (n < NE) ? (Wr + n) : (Wn + (n - NE));
    union { short8 s; ushort_t us[8]; } H, L;
#pragma unroll
    for (int j = 0; j < 8; ++j) {
        const float v = src[(size_t)(k0 + j) * NE];
        const unsigned uv = __float_as_uint(v);
        const unsigned hb = (uv + 0x7fffu + ((uv >> 16) & 1u)) & 0xffff0000u;
        const float lo = v - __uint_as_float(hb);
        const unsigned ul = __float_as_uint(lo);
        H.us[j] = (ushort_t)(hb >> 16);
        L.us[j] = (ushort_t)((ul + 0x7fffu + ((ul >> 16) & 1u)) >> 16);
    }
    const size_t s0 = (size_t)(kcg * 8 + ct) * 2;     // slot pair index
    *(short8*)(wsW + s0 * 512 + l * 8)         = H.s;
    *(short8*)(wsW + (s0 + 1) * 512 + l * 8)   = L.s;
}

// B fragments for one chunk, double-buffered in registers across chunks.
struct BFrag { short8 h[2][2]; short8 l[2][2]; };

__device__ __forceinline__ void load_b(const char* __restrict__ wsB,
                                       int ch, int w, int lane, BFrag& b) {
#pragma unroll
    for (int kc = 0; kc < 2; ++kc)
#pragma unroll
        for (int cc = 0; cc < 2; ++cc) {
            const size_t off = (size_t)(((ch * 2 + kc) * 8) + 2 * w + cc) * 2048
                             + (size_t)lane * 16;
            b.h[kc][cc] = *(const short8*)(wsB + off);
            b.l[kc][cc] = *(const short8*)(wsB + off + 1024);
        }
}

template<int W>
__device__ __forceinline__ void wait_vm() {
    static_assert(W == 11 || W == 19 || W == 27, "unexpected wait");
    if constexpr (W == 11)      asm volatile("s_waitcnt vmcnt(11)" ::: "memory");
    else if constexpr (W == 19) asm volatile("s_waitcnt vmcnt(19)" ::: "memory");
    else                        asm volatile("s_waitcnt vmcnt(27)" ::: "memory");
}

// one row-tile (16 rows) x 2 col-tiles x 64 k — asm ds_reads + explicit waits
__device__ __forceinline__ void compute_chunk(unsigned ldsb,
                                              const unsigned (&aoffB)[2][2],
                                              const BFrag& b,
                                              float4_ (&acc)[2]) {
    const float4_ va0 = ds_read128(ldsb + aoffB[0][0]);
    const float4_ vb0 = ds_read128(ldsb + aoffB[0][1]);
    const float4_ va1 = ds_read128(ldsb + aoffB[1][0]);
    const float4_ vb1 = ds_read128(ldsb + aoffB[1][1]);
    asm volatile("s_waitcnt lgkmcnt(0)" ::: "memory");
    __builtin_amdgcn_sched_barrier(0);   // rule #18: pin MFMA/cvt below the wait
    short8 ah0, al0, ah1, al1;
    cvt8(va0, vb0, &ah0, &al0);
    cvt8(va1, vb1, &ah1, &al1);
#pragma unroll
    for (int cc = 0; cc < 2; ++cc) {
        acc[cc] = __builtin_amdgcn_mfma_f32_16x16x32_bf16(ah0, b.h[0][cc], acc[cc], 0, 0, 0);
        acc[cc] = __builtin_amdgcn_mfma_f32_16x16x32_bf16(al0, b.h[0][cc], acc[cc], 0, 0, 0);
        acc[cc] = __builtin_amdgcn_mfma_f32_16x16x32_bf16(ah0, b.l[0][cc], acc[cc], 0, 0, 0);
    }
#pragma unroll
    for (int cc = 0; cc < 2; ++cc) {
        acc[cc] = __builtin_amdgcn_mfma_f32_16x16x32_bf16(ah1, b.h[1][cc], acc[cc], 0, 0, 0);
        acc[cc] = __builtin_amdgcn_mfma_f32_16x16x32_bf16(al1, b.h[1][cc], acc[cc], 0, 0, 0);
        acc[cc] = __builtin_amdgcn_mfma_f32_16x16x32_bf16(ah1, b.l[1][cc], acc[cc], 0, 0, 0);
    }
}

// One pipeline step for chunk i. Issue order (pinned by SBs): B(i+1):8, S(i+3):1
// -> every step adds exactly 9 VMEM ops. vmcnt(W) with W = #ops issued after S(i)
// guarantees S(i) retired (in-order retirement), W = 11/19/27 for i=0/1/>=2.
template<int W>
__device__ __forceinline__ void step(int i, const char* wsB, int w, int lane,
                                     BFrag& bload, const BFrag& buse,
                                     const float* gxb, float* smem, int lxo,
                                     unsigned ldsbase, const unsigned (&aoffB)[2][2],
                                     float4_ (&acc)[2])
{
    const int bch = (i + 1 < NCHUNK) ? i + 1 : NCHUNK - 1;
    load_b(wsB, bch, w, lane, bload);
    __builtin_amdgcn_sched_barrier(0);
    const int sch = (i + 3 < NCHUNK) ? i + 3 : NCHUNK - 1;   // tail: restage 31
    async16(gxb + sch * DC, &smem[((i + 3) & (NBUF - 1)) * 1024 + lxo]);
    __builtin_amdgcn_sched_barrier(0);
    wait_vm<W>();                       // own S(i) retired
    __builtin_amdgcn_s_barrier();       // all waves' S(i) in LDS
    __builtin_amdgcn_sched_barrier(0);
    compute_chunk(ldsbase + (unsigned)((i & (NBUF - 1)) * 4096), aoffB, buse, acc);
}

__global__ __launch_bounds__(NTHREADS, 4)
void moe_main(const float* __restrict__ x,
              const float* __restrict__ br,
              const float* __restrict__ bn,
              const float* __restrict__ noise_eps,
              const float* __restrict__ gumbel,
              const ushort_t* __restrict__ wsW,
              float* __restrict__ out)
{
    // x stage ring: 8 x 1024 floats (32 KB); epilogue reuses [0..4671]
    __shared__ __align__(16) float smem[NBUF * 1024];

    const int t    = threadIdx.x;
    const int lane = t & 63;
    const int w    = t >> 6;          // wave 0..3, owns col-tiles {2w, 2w+1}
    const int c4   = lane & 15;
    const int q    = lane >> 4;
    const int row0 = blockIdx.x * ROWS;

    // x staging: 4 issues/chunk, wave w does issue i=w covering rows 4w..4w+3
    // lane l -> row 4w+(l>>4); LDS granule pos p=l&15 holds gk = p^(row&15)
    const int  srow = 4 * w + q;
    const int  sgk  = c4 ^ (srow & 15);
    const float* gxb = x + (size_t)(row0 + srow) * DIM + sgk * 4;
    const int  lxo  = w * 256;        // float offset within a stage buffer

    // A-read byte offsets (chunk-invariant): row m=c4, granules (kc*8+q*2)^c4, +1^c4
    unsigned aoffB[2][2];
#pragma unroll
    for (int kc = 0; kc < 2; ++kc) {
        const int g0 = kc * 8 + q * 2;
        aoffB[kc][0] = (unsigned)((c4 * 64 + ((g0 ^ c4) * 4)) * 4);
        aoffB[kc][1] = (unsigned)((c4 * 64 + (((g0 + 1) ^ c4) * 4)) * 4);
    }
    const unsigned ldsbase =
        (unsigned)(unsigned long long)(__attribute__((address_space(3))) void*)(void*)smem;

    float4_ acc[2];
    acc[0] = (float4_)(0.f);
    acc[1] = (float4_)(0.f);

    const char* wsB = (const char*)wsW;

    // ---- prologue: B(0) then S0,S1,S2 (order pinned for vmcnt accounting) ----
    BFrag bA, bB;
    load_b(wsB, 0, w, lane, bA);
    __builtin_amdgcn_sched_barrier(0);
    async16(gxb + 0 * DC, &smem[0 * 1024 + lxo]);
    __builtin_amdgcn_sched_barrier(0);
    async16(gxb + 1 * DC, &smem[1 * 1024 + lxo]);
    __builtin_amdgcn_sched_barrier(0);
    async16(gxb + 2 * DC, &smem[2 * 1024 + lxo]);
    __builtin_amdgcn_sched_barrier(0);

    // ---- peeled steps 0,1; then uniform steady loop ----
    step<11>(0, wsB, w, lane, bB, bA, gxb, smem, lxo, ldsbase, aoffB, acc);
    step<19>(1, wsB, w, lane, bA, bB, gxb, smem, lxo, ldsbase, aoffB, acc);
#pragma unroll 1
    for (int i = 2; i < NCHUNK; i += 2) {
        step<27>(i,     wsB, w, lane, bB, bA, gxb, smem, lxo, ldsbase, aoffB, acc);
        step<27>(i + 1, wsB, w, lane, bA, bB, gxb, smem, lxo, ldsbase, aoffB, acc);
    }

    // prefetch per-row randomness early (overlaps epilogue barrier+transpose)
    float epsv[4], gumv[4];
#pragma unroll
    for (int r = 0; r < 4; ++r) {
        const int row = row0 + w * 4 + r;
        epsv[r] = noise_eps[(size_t)row * NE + lane];
        gumv[r] = gumbel  [(size_t)row * NE + lane];
    }

    // ---- epilogue: transpose C tiles through LDS, then per-row wave ops ----
    __syncthreads();                   // full drain (stage/B tails); reuse LDS
    float* rawS = &smem[0];            // 16 x 65 (padded)
    float* noiS = &smem[2080];         // 16 x 65
#pragma unroll
    for (int cc = 0; cc < 2; ++cc) {
        const int colg = (2 * w + cc) * 16 + c4;   // 0..127; <64 raw else noise
        float* basep = (colg < NE) ? rawS : noiS;
        const int col = colg & 63;
#pragma unroll
        for (int v = 0; v < 4; ++v) {
            const int row = q * 4 + v;             // C/D: col=lane&15, row=quad*4+reg
            basep[row * 65 + col] = acc[cc][v];
        }
    }
    __syncthreads();

    const float br_l = br[lane];
    const float bn_l = bn[lane];

    float imp_acc = 0.f, load_acc = 0.f;
    float* out_em   = out;
    float* out_rp   = out + (size_t)N_TOK * NE;
    float* out_imp  = out + (size_t)2 * N_TOK * NE;
    float* out_load = out_imp + NE;

#pragma unroll 1
    for (int r = 0; r < 4; ++r) {
        const int lrow = w * 4 + r;
        const int row  = row0 + lrow;
        const float raw = rawS[lrow * 65 + lane] + br_l;
        const float nl  = noiS[lrow * 65 + lane] + bn_l;
        const float sd = fmaxf(nl, 0.f) + log1pf(expf(-fabsf(nl))) + 0.01f;
        const float noisy = fmaf(epsv[r], sd, raw);

        // ---- threshold = 9th largest via ballot binary search (bit-exact) ----
        const unsigned uk  = __float_as_uint(noisy);
        const unsigned key = uk ^ ((uk & 0x80000000u) ? 0xFFFFFFFFu : 0x80000000u);
        unsigned res = 0;
#pragma unroll
        for (int bit = 31; bit >= 0; --bit) {
            const unsigned cand = res | (1u << bit);
            const int cnt = __popcll(__ballot(key >= cand));
            if (cnt >= TOPK) res = cand;
        }
        const float thr  = __uint_as_float(res ^ ((res & 0x80000000u) ? 0x80000000u : 0xFFFFFFFFu));
        const float hard = (key >= res) ? 1.f : 0.f;

        // fused reductions: one dual-max chain, one triple-sum chain
        const float g = noisy + gumv[r];
        float mg = g, mr = raw;
        wave_max64_2(mg, mr);

        const float eg = expf(g - mg);
        const float en = expf(noisy - thr);   // softmax shift-invariant
        const float er = expf(raw - mr);
        float sg = eg, sn = en, sr = er;
        wave_sum64_3(sg, sn, sr);

        const float ms = eg / sg;
        const float em = (hard - ms) + ms;
        const float rp = en / sn;
        imp_acc += er / sr;

        const float z = (thr - raw) / sd;
        load_acc += 0.5f * erfcf(z * 45.254833995939045f);

        out_em[(size_t)row * NE + lane] = em;
        out_rp[(size_t)row * NE + lane] = rp;
    }

    __syncthreads();                   // rawS/noiS reads done; reuse for reduction
    smem[w * 64 + lane]       = imp_acc;
    smem[256 + w * 64 + lane] = load_acc;
    __syncthreads();
    if (w == 0) {
        const float s1 = smem[lane] + smem[64 + lane] + smem[128 + lane] + smem[192 + lane];
        const float s2 = smem[256 + lane] + smem[320 + lane] + smem[384 + lane] + smem[448 + lane];
        atomicAdd(&out_imp[lane], s1);
        atomicAdd(&out_load[lane], s2);
    }
}

extern "C" void kernel_launch(void* const* d_in, const int* in_sizes, int n_in,
                              void* d_out, int out_size, void* d_ws, size_t ws_size,
                              hipStream_t stream)
{
    const float* x         = (const float*)d_in[0];
    const float* Wr        = (const float*)d_in[1];
    const float* br        = (const float*)d_in[2];
    const float* Wn        = (const float*)d_in[3];
    const float* bn        = (const float*)d_in[4];
    const float* noise_eps = (const float*)d_in[5];
    const float* gumbel    = (const float*)d_in[6];
    float* out = (float*)d_out;
    ushort_t* wsW = (ushort_t*)d_ws;   // 1 MB (64*8*2 slots x 1 KB)

    (void)hipMemsetAsync((char*)d_out + (size_t)2 * N_TOK * NE * sizeof(float), 0,
                         2 * NE * sizeof(float), stream);
    prep_w<<<128, 256, 0, stream>>>(Wr, Wn, wsW);
    moe_main<<<N_TOK / ROWS, NTHREADS, 0, stream>>>(
        x, br, bn, noise_eps, gumbel, wsW, out);
}